// Round 8
// baseline (1162.922 us; speedup 1.0000x reference)
//
#include <hip/hip_runtime.h>

typedef __bf16 bf16x8 __attribute__((ext_vector_type(8)));
typedef __bf16 bf16x4 __attribute__((ext_vector_type(4)));
typedef float  f32x4  __attribute__((ext_vector_type(4)));
typedef float  f32x16 __attribute__((ext_vector_type(16)));
typedef unsigned int  uint;
typedef unsigned short ushort_t;

static __device__ __forceinline__ ushort_t f2bf(float f) {
    uint u = __float_as_uint(f);
    return (ushort_t)((u + 0x7fffu + ((u >> 16) & 1u)) >> 16);
}
static __device__ __forceinline__ float bf2f(ushort_t u) {
    return __uint_as_float((uint)u << 16);
}
static __device__ __forceinline__ f32x4 up4(uint2 p) {   // 4 bf16 -> f32x4
    f32x4 r;
    r[0] = __uint_as_float(p.x << 16);
    r[1] = __uint_as_float(p.x & 0xffff0000u);
    r[2] = __uint_as_float(p.y << 16);
    r[3] = __uint_as_float(p.y & 0xffff0000u);
    return r;
}

// ---------------- problem constants ----------------
// conv1: (32,1,120,640) * (256,1,30,160) stride (1,4) -> use 90x120 region
// prim : X(b,h,w,ic) * (256,256,10,10) stride 10 -> (32,256,9,12)
// caps : u(32,3456,8) -> u_predict(32,3456,5,16) bf16 -> routing -> (32,5,26) log_softmax

// ws layout (bytes)
constexpr size_t OFF_W1F = 0;
constexpr size_t SZ_W1F  = (size_t)256 * 4800 * 2;            //  2,457,600 (frag-major 32x32)
constexpr size_t OFF_A2  = OFF_W1F + SZ_W1F;
constexpr size_t SZ_A2   = (size_t)256 * 25600 * 2;           // 13,107,200
constexpr size_t OFF_X   = OFF_A2 + SZ_A2;
constexpr size_t SZ_X    = (size_t)32 * 90 * 120 * 256 * 2;   // 176,947,200
constexpr size_t OFF_P   = OFF_X + SZ_X;
constexpr size_t SZ_P    = (size_t)8 * 256 * 32 * 112 * 2;    // 14,680,064 (bf16, s=8)
// tail scratch aliases the X region (X dead after k2):
constexpr size_t OFF_UP  = OFF_X;                             // bf16 [32][3456][80] = 17.7 MB
constexpr size_t OFF_BB  = OFF_X + (size_t)24 * 1024 * 1024;  // fp32 [32][3456][5]  = 2.2 MB
constexpr size_t OFF_S0  = OFF_X + (size_t)28 * 1024 * 1024;  // fp32 [32][27][80]   = 276 KB
constexpr size_t OFF_S1  = OFF_X + (size_t)29 * 1024 * 1024;
constexpr size_t WS_NEED = OFF_P + SZ_P;                      // ~207 MB (unchanged)

// ---------------- K0a: conv1_w -> bf16, 32x32x16-fragment-major (r4-verified layout) -----
// frag q = (kh*8 + ocb)*10 + kc; lane element j:
//   w1[(ocb*32 + (lane&31))*4800 + kh*160 + kc*16 + (lane>>5)*8 + j] -> w1f[q*512 + lane*8 + j]
__global__ void k0_w1(const float* __restrict__ w, ushort_t* __restrict__ o) {
    int t = blockIdx.x * 256 + threadIdx.x;   // grid 600*256 == 153,600 exactly
    int l  = t & 63;
    int q  = t >> 6;                           // 0..2399
    int kc  = q % 10;
    int ocb = (q / 10) % 8;
    int kh  = q / 80;
    const float* src = w + (size_t)(ocb * 32 + (l & 31)) * 4800 + kh * 160 + kc * 16 + (l >> 5) * 8;
    float4 f0 = *(const float4*)src;
    float4 f1 = *(const float4*)(src + 4);
    uint4 pk;
    pk.x = (uint)f2bf(f0.x) | ((uint)f2bf(f0.y) << 16);
    pk.y = (uint)f2bf(f0.z) | ((uint)f2bf(f0.w) << 16);
    pk.z = (uint)f2bf(f1.x) | ((uint)f2bf(f1.y) << 16);
    pk.w = (uint)f2bf(f1.z) | ((uint)f2bf(f1.w) << 16);
    *(uint4*)&o[(size_t)t * 8] = pk;
}

// ---------------- K0b: prim_w (oc2,ic,ph,pw) -> A2[oc2][p*256+ic] bf16 ----------------
__global__ void k0_a2(const float* __restrict__ w, ushort_t* __restrict__ o) {
    __shared__ ushort_t l[25600];
    int oc2 = blockIdx.x;                     // grid 256
    const float* src = w + (size_t)oc2 * 25600;
    for (int idx = threadIdx.x; idx < 25600; idx += 256) l[idx] = f2bf(src[idx]); // idx = ic*100+p
    __syncthreads();
    ushort_t* dst = o + (size_t)oc2 * 25600;
    for (int idx = threadIdx.x; idx < 25600; idx += 256) {    // idx = p*256+ic (coalesced write)
        int p = idx >> 8, ic = idx & 255;
        dst[idx] = l[ic * 100 + p];
    }
}

// ---------------- K1: conv1+bias+relu (v6: v3 skeleton + 32x32x16 MFMA) ----------------
// grid (90, 32) = (h, b); 256 threads = 4 waves, wave tile 64 oc x 128 w (120 valid).
// mt in {0,1}: 32-oc blocks (ocb = wid*2+mt, per-wave distinct -> A dedup preserved);
// nt in 0..3: 32-w blocks. acc[2][4] f32x16 = 128 AGPRs (same budget as v3).
// A frags: coalesced dwordx4 from w1f-32 (L2). B: 30 rows staged once; barrier-free K-loop.
// Fragment mappings (A/B/C) verified numerically in r4. Rate: 2382 vs 2075 TF (+15%).
// REGISTER NOTE: 2 waves/SIMD hard cap; do NOT raise min-waves (r5: acc spill, 85 GB HBM).
__global__ __launch_bounds__(256, 2) void k1_conv1(const float* __restrict__ inp,
                                                   const ushort_t* __restrict__ w1f,
                                                   const float* __restrict__ cb,
                                                   ushort_t* __restrict__ X) {
    __shared__ ushort_t smem[31680];          // 63,360 B
    ushort_t* brow = smem;                    // [30][704], cols 640..703 zero
    const int tid = threadIdx.x, lane = tid & 63, wid = tid >> 6;
    const int wm = wid * 64;                  // wave oc base: 0/64/128/192
    const int h = blockIdx.x, b = blockIdx.y;
    const int l32 = lane & 31, hi8 = (lane >> 5) * 8, hi4 = (lane >> 5) * 4;
    f32x16 acc[2][4] = {};                    // [mt][nt]

    // stage 30 input rows (h..h+29) as bf16, cols 640..703 zeroed (v3 verbatim)
    for (int idx = tid; idx < 5280; idx += 256) {
        int r = idx / 176, c = idx % 176;
        uint2 pk; pk.x = 0u; pk.y = 0u;
        if (c < 160) {
            const float* irow = inp + ((size_t)b * 120 + h + r) * 640;
            float4 f = *(const float4*)&irow[c * 4];
            pk.x = (uint)f2bf(f.x) | ((uint)f2bf(f.y) << 16);
            pk.y = (uint)f2bf(f.z) | ((uint)f2bf(f.w) << 16);
        }
        *(uint2*)&brow[r * 704 + c * 4] = pk;
    }
    __syncthreads();

    const int bb0 = 4 * l32 + hi8;
#pragma unroll 1
    for (int kh = 0; kh < 30; ++kh) {
        const int rb = kh * 704 + bb0;
        const ushort_t* wbase = w1f + (size_t)((kh * 8 + wid * 2) * 10) * 512 + lane * 8;
#pragma unroll
        for (int kc = 0; kc < 10; ++kc) {
            bf16x8 bfr[4];
#pragma unroll
            for (int nt = 0; nt < 4; ++nt) {
                union { bf16x8 v8; bf16x4 v4[2]; } fr;
                fr.v4[0] = *(const bf16x4*)&brow[rb + nt * 128 + kc * 16];
                fr.v4[1] = *(const bf16x4*)&brow[rb + nt * 128 + kc * 16 + 4];
                bfr[nt] = fr.v8;
            }
#pragma unroll
            for (int mt = 0; mt < 2; ++mt) {
                bf16x8 af = *(const bf16x8*)&wbase[(size_t)(mt * 10 + kc) * 512];
#pragma unroll
                for (int nt = 0; nt < 4; ++nt)
                    acc[mt][nt] = __builtin_amdgcn_mfma_f32_32x32x16_bf16(af, bfr[nt], acc[mt][nt], 0, 0, 0);
            }
        }
    }

    // bias: C row = (r&3) + 8*(r>>2) + 4*(lane>>5), col(w) = lane&31 (r4-verified)
    float cbv[2][16];
#pragma unroll
    for (int mt = 0; mt < 2; ++mt)
#pragma unroll
        for (int r = 0; r < 16; ++r)
            cbv[mt][r] = cb[wm + mt * 32 + (r & 3) + 8 * (r >> 2) + hi4];
    __syncthreads();                          // brow dead; cs aliases smem
    ushort_t* cs = smem;                      // [120][264]
#pragma unroll
    for (int nt = 0; nt < 4; ++nt) {
        int w = nt * 32 + l32;
        if (w < 120) {
#pragma unroll
            for (int mt = 0; mt < 2; ++mt)
#pragma unroll
                for (int r = 0; r < 16; ++r) {
                    int oc = wm + mt * 32 + (r & 3) + 8 * (r >> 2) + hi4;
                    float v = acc[mt][nt][r] + cbv[mt][r];
                    v = v > 0.f ? v : 0.f;
                    cs[w * 264 + oc] = f2bf(v);
                }
        }
    }
    __syncthreads();
    ushort_t* Xbase = X + ((size_t)b * 90 + h) * 120 * 256;
    for (int idx = tid; idx < 3840; idx += 256) {            // 120*256/8 chunks
        int w = idx >> 5, c = (idx & 31) * 8;
        *(uint4*)&Xbase[(size_t)w * 256 + c] = *(const uint4*)&cs[w * 264 + c];
    }
}

// ---------------- K2: prim conv GEMM, split-K s=8, barrier-free (v4) ----------------
// grid (2, 8, 32) = (oc2 half, split, b); 256 thr = 4 waves, each owning a distinct
// 32-oc slice x 112 n x the s-range of p. Patch positions partition X exactly, so no
// cross-wave reduction is needed: no LDS, no barriers. P[s][oc2][b][n] bf16.
// 2 blocks/CU -> 4 waves/SIMD; X frags shared by all 4 waves (L1), A2 per-wave distinct.
__global__ __launch_bounds__(256) void k2_prim(const ushort_t* __restrict__ X,
                                               const ushort_t* __restrict__ A2,
                                               ushort_t* __restrict__ P) {
    const int tid = threadIdx.x, lane = tid & 63, wid = tid >> 6;
    const int mi = blockIdx.x, s = blockIdx.y, b = blockIdx.z;
    const int msub = mi * 128 + wid * 32;
    const int l16 = lane & 15, g8 = (lane >> 4) * 8;
    f32x4 acc[2][7] = {};
    size_t aoff[2];
#pragma unroll
    for (int t = 0; t < 2; ++t) aoff[t] = (size_t)(msub + t * 16 + l16) * 25600 + g8;
    size_t noff[7];
#pragma unroll
    for (int nt = 0; nt < 7; ++nt) {
        int n = nt * 16 + l16; n = n < 108 ? n : 107;   // pad cols clamp
        int h2 = n / 12, w2 = n % 12;
        noff[nt] = (((size_t)b * 90 + 10 * h2) * 120 + 10 * w2) * 256 + g8;
    }
    const int p0 = (100 * s) / 8, p1 = (100 * (s + 1)) / 8;
#pragma unroll 1
    for (int p = p0; p < p1; ++p) {
        int ph = p / 10, pw = p % 10;
        size_t xb = (size_t)(ph * 120 + pw) * 256;
        size_t ab = (size_t)p * 256;
#pragma unroll
        for (int icc = 0; icc < 8; ++icc) {
            bf16x8 af[2], bfr[7];
#pragma unroll
            for (int t = 0; t < 2; ++t)
                af[t] = *(const bf16x8*)&A2[aoff[t] + ab + icc * 32];
#pragma unroll
            for (int nt = 0; nt < 7; ++nt)
                bfr[nt] = *(const bf16x8*)&X[noff[nt] + xb + icc * 32];
#pragma unroll
            for (int t = 0; t < 2; ++t)
#pragma unroll
                for (int nt = 0; nt < 7; ++nt)
                    acc[t][nt] = __builtin_amdgcn_mfma_f32_16x16x32_bf16(af[t], bfr[nt], acc[t][nt], 0, 0, 0);
        }
    }
#pragma unroll
    for (int t = 0; t < 2; ++t)
#pragma unroll
        for (int nt = 0; nt < 7; ++nt)
#pragma unroll
            for (int r = 0; r < 4; ++r) {
                int n   = nt * 16 + l16;
                int oc2 = msub + t * 16 + (lane >> 4) * 4 + r;
                P[(((size_t)s * 256 + oc2) * 32 + b) * 112 + n] = f2bf(acc[t][nt][r]);
            }
}

// ---------------- K3: reduce partials + prim bias + squash + caps prediction ----------------
// r6 mapping: b-interleaved, lanes 0..31 share one caps_w row (broadcast loads).
// P b-scatter costs ~13 us of L2 traffic; caps_w broadcast saves ~1 GB (r7 lesson).
__global__ __launch_bounds__(256) void k3_caps(const ushort_t* __restrict__ P,
                                               const float* __restrict__ prim_b,
                                               const float* __restrict__ caps_w,
                                               ushort_t* __restrict__ UP) {
    int t = blockIdx.x * 256 + threadIdx.x;   // grid 432*256 == 110,592 exactly
    int b = t & 31, i = t >> 5;
    int cap = i / 108, hw = i % 108;
    float ud[8], l2 = 0.f;
#pragma unroll
    for (int d = 0; d < 8; ++d) {
        int oc2 = cap * 8 + d;
        float v = prim_b[oc2];
#pragma unroll
        for (int s = 0; s < 8; ++s)
            v += bf2f(P[(((size_t)s * 256 + oc2) * 32 + b) * 112 + hw]);
        ud[d] = v; l2 += v * v;
    }
    float scale = sqrtf(l2) / (1.f + l2);     // squash factor
#pragma unroll
    for (int d = 0; d < 8; ++d) ud[d] *= scale;
    const float* cw = caps_w + (size_t)i * 640;
    ushort_t* up = UP + ((size_t)b * 3456 + i) * 80;
    for (int j = 0; j < 80; j += 4) {
        f32x4 o = {0.f, 0.f, 0.f, 0.f};
#pragma unroll
        for (int d = 0; d < 8; ++d) {
            f32x4 w = *(const f32x4*)&cw[d * 80 + j];
            o += ud[d] * w;
        }
        uint2 pk;
        pk.x = (uint)f2bf(o[0]) | ((uint)f2bf(o[1]) << 16);
        pk.y = (uint)f2bf(o[2]) | ((uint)f2bf(o[3]) << 16);
        *(uint2*)&up[j] = pk;
    }
}

// ---------------- K4 iteration: (optional v from spIn) + b-update + softmax + partial s ----
// grid (27, 32) x 128 thr; thread owns i = chunk*128+tid.
// flags: 1 = reduce spIn -> v and add u.v to b; 2 = read b from BB (else b_route); 4 = write BB
__global__ __launch_bounds__(128) void k4_iter(const ushort_t* __restrict__ UP,
                                               const float* __restrict__ b_route,
                                               float* __restrict__ BB,
                                               const float* __restrict__ spIn,
                                               float* __restrict__ spOut,
                                               int flags) {
    __shared__ __attribute__((aligned(16))) float sv[80];
    __shared__ float sred[2][80];
    __shared__ float sscale[5];
    const int tid = threadIdx.x, lane = tid & 63, wv = tid >> 6;
    const int chunk = blockIdx.x, b = blockIdx.y;

    if (flags & 1) {                          // reduce previous partials -> v (redundant per block, cheap)
        if (tid < 80) {
            float s = 0.f;
            for (int c2 = 0; c2 < 27; ++c2) s += spIn[((size_t)b * 27 + c2) * 80 + tid];
            sv[tid] = s;
        }
        __syncthreads();
        if (tid < 5) {
            float l2 = 0.f;
            for (int d = 0; d < 16; ++d) { float x = sv[tid * 16 + d]; l2 += x * x; }
            sscale[tid] = sqrtf(l2) / (1.f + l2);
        }
        __syncthreads();
        if (tid < 80) sv[tid] *= sscale[tid / 16];
    }
    __syncthreads();

    const int i = chunk * 128 + tid;
    const ushort_t* up = UP + ((size_t)b * 3456 + i) * 80;
    f32x4 u4[20];
#pragma unroll
    for (int r = 0; r < 20; ++r) u4[r] = up4(*(const uint2*)&up[r * 4]);

    float bo[5];
#pragma unroll
    for (int o = 0; o < 5; ++o) {
        float bv = (flags & 2) ? BB[((size_t)b * 3456 + i) * 5 + o] : b_route[i * 5 + o];
        if (flags & 1) {
            f32x4 dv = u4[o * 4 + 0] * (*(const f32x4*)&sv[o * 16 + 0])
                     + u4[o * 4 + 1] * (*(const f32x4*)&sv[o * 16 + 4])
                     + u4[o * 4 + 2] * (*(const f32x4*)&sv[o * 16 + 8])
                     + u4[o * 4 + 3] * (*(const f32x4*)&sv[o * 16 + 12]);
            bv += dv[0] + dv[1] + dv[2] + dv[3];
        }
        if (flags & 4) BB[((size_t)b * 3456 + i) * 5 + o] = bv;
        bo[o] = bv;
    }
    float m = fmaxf(fmaxf(fmaxf(bo[0], bo[1]), fmaxf(bo[2], bo[3])), bo[4]);
    float e[5], sum = 0.f;
#pragma unroll
    for (int o = 0; o < 5; ++o) { e[o] = __expf(bo[o] - m); sum += e[o]; }
    float inv = 1.f / sum;
    f32x4 a4[20];
#pragma unroll
    for (int o = 0; o < 5; ++o) {
        float c = e[o] * inv;
#pragma unroll
        for (int q = 0; q < 4; ++q) a4[o * 4 + q] = c * u4[o * 4 + q];
    }
    // reduce across 128 threads
#pragma unroll
    for (int off = 32; off >= 1; off >>= 1)
#pragma unroll
        for (int q = 0; q < 20; ++q)
#pragma unroll
            for (int c = 0; c < 4; ++c) a4[q][c] += __shfl_xor(a4[q][c], off, 64);
    if (lane == 0)
#pragma unroll
        for (int q = 0; q < 20; ++q)
#pragma unroll
            for (int c = 0; c < 4; ++c) sred[wv][q * 4 + c] = a4[q][c];
    __syncthreads();
    if (tid < 80) spOut[((size_t)b * 27 + chunk) * 80 + tid] = sred[0][tid] + sred[1][tid];
}

// ---------------- K4 final: reduce -> v -> logits -> log_softmax ----------------
__global__ __launch_bounds__(192) void k4_fin(const float* __restrict__ spIn,
                                              const float* __restrict__ pred_w,
                                              const float* __restrict__ pred_b,
                                              const float* __restrict__ eos_w,
                                              const float* __restrict__ eos_b,
                                              float* __restrict__ out) {
    __shared__ __attribute__((aligned(16))) float sv[80];
    __shared__ float sscale[5];
    __shared__ float lg[130];
    __shared__ float lse[5];
    const int tid = threadIdx.x, b = blockIdx.x;
    if (tid < 80) {
        float s = 0.f;
        for (int c2 = 0; c2 < 27; ++c2) s += spIn[((size_t)b * 27 + c2) * 80 + tid];
        sv[tid] = s;
    }
    __syncthreads();
    if (tid < 5) {
        float l2 = 0.f;
        for (int d = 0; d < 16; ++d) { float x = sv[tid * 16 + d]; l2 += x * x; }
        sscale[tid] = sqrtf(l2) / (1.f + l2);
    }
    __syncthreads();
    if (tid < 80) sv[tid] *= sscale[tid / 16];
    __syncthreads();
    if (tid < 130) {
        int o = tid / 26, j = tid % 26;
        const float* wv = (j < 25) ? &pred_w[j * 16] : &eos_w[0];
        float dot = (j < 25) ? pred_b[j] : eos_b[0];
        for (int d = 0; d < 16; ++d) dot += sv[o * 16 + d] * wv[d];
        lg[tid] = dot;
    }
    __syncthreads();
    if (tid < 5) {
        float m = lg[tid * 26];
        for (int j = 1; j < 26; ++j) m = fmaxf(m, lg[tid * 26 + j]);
        float sum = 0.f;
        for (int j = 0; j < 26; ++j) sum += expf(lg[tid * 26 + j] - m);
        lse[tid] = m + logf(sum);
    }
    __syncthreads();
    if (tid < 130) out[b * 130 + tid] = lg[tid] - lse[tid / 26];
}

// ---------------- launch ----------------
extern "C" void kernel_launch(void* const* d_in, const int* in_sizes, int n_in,
                              void* d_out, int out_size, void* d_ws, size_t ws_size,
                              hipStream_t stream) {
    const float* inp    = (const float*)d_in[0];
    const float* w1     = (const float*)d_in[1];
    const float* cb1    = (const float*)d_in[2];
    const float* w2     = (const float*)d_in[3];
    const float* pb2    = (const float*)d_in[4];
    const float* capsw  = (const float*)d_in[5];
    const float* broute = (const float*)d_in[6];
    const float* predw  = (const float*)d_in[7];
    const float* predb  = (const float*)d_in[8];
    const float* eosw   = (const float*)d_in[9];
    const float* eosb   = (const float*)d_in[10];
    float* out = (float*)d_out;
    char* ws = (char*)d_ws;
    if (ws_size < WS_NEED) return;

    ushort_t* w1f = (ushort_t*)(ws + OFF_W1F);
    ushort_t* a2  = (ushort_t*)(ws + OFF_A2);
    ushort_t* X   = (ushort_t*)(ws + OFF_X);
    ushort_t* P   = (ushort_t*)(ws + OFF_P);
    ushort_t* UP  = (ushort_t*)(ws + OFF_UP);
    float*    BB  = (float*)(ws + OFF_BB);
    float*    S0  = (float*)(ws + OFF_S0);
    float*    S1  = (float*)(ws + OFF_S1);

    k0_w1   <<<dim3(600),      dim3(256), 0, stream>>>(w1, w1f);
    k0_a2   <<<dim3(256),      dim3(256), 0, stream>>>(w2, a2);
    k1_conv1<<<dim3(90, 32),   dim3(256), 0, stream>>>(inp, w1f, cb1, X);
    k2_prim <<<dim3(2, 8, 32), dim3(256), 0, stream>>>(X, a2, P);
    k3_caps <<<dim3(432),      dim3(256), 0, stream>>>(P, pb2, capsw, UP);
    // routing: it0 (initial c/s/v) .. it3; partials double-buffered S0/S1
    k4_iter <<<dim3(27, 32),   dim3(128), 0, stream>>>(UP, broute, BB, S1, S0, 0);         // s0
    k4_iter <<<dim3(27, 32),   dim3(128), 0, stream>>>(UP, broute, BB, S0, S1, 1 | 4);     // v0; b1; s1
    k4_iter <<<dim3(27, 32),   dim3(128), 0, stream>>>(UP, broute, BB, S1, S0, 1 | 2 | 4); // v1; b2; s2
    k4_iter <<<dim3(27, 32),   dim3(128), 0, stream>>>(UP, broute, BB, S0, S1, 1 | 2);     // v2; b3; s3
    k4_fin  <<<dim3(32),       dim3(192), 0, stream>>>(S1, predw, predb, eosw, eosb, out);
}

// Round 9
// 1024.269 us; speedup vs baseline: 1.1354x; 1.1354x over previous
//
#include <hip/hip_runtime.h>

typedef __bf16 bf16x8 __attribute__((ext_vector_type(8)));
typedef __bf16 bf16x4 __attribute__((ext_vector_type(4)));
typedef float  f32x4  __attribute__((ext_vector_type(4)));
typedef unsigned int  uint;
typedef unsigned short ushort_t;

static __device__ __forceinline__ ushort_t f2bf(float f) {
    uint u = __float_as_uint(f);
    return (ushort_t)((u + 0x7fffu + ((u >> 16) & 1u)) >> 16);
}
static __device__ __forceinline__ float bf2f(ushort_t u) {
    return __uint_as_float((uint)u << 16);
}
static __device__ __forceinline__ f32x4 up4(uint2 p) {   // 4 bf16 -> f32x4
    f32x4 r;
    r[0] = __uint_as_float(p.x << 16);
    r[1] = __uint_as_float(p.x & 0xffff0000u);
    r[2] = __uint_as_float(p.y << 16);
    r[3] = __uint_as_float(p.y & 0xffff0000u);
    return r;
}

// ---------------- problem constants ----------------
// conv1: (32,1,120,640) * (256,1,30,160) stride (1,4) -> use 90x120 region
// prim : X(b,h,w,ic) * (256,256,10,10) stride 10 -> (32,256,9,12)
// caps : u(32,3456,8) -> u_predict(32,3456,5,16) bf16 -> routing -> (32,5,26) log_softmax

// ws layout (bytes)
constexpr size_t OFF_W1F = 0;
constexpr size_t SZ_W1F  = (size_t)256 * 4800 * 2;            //  2,457,600 (frag-major 16x16)
constexpr size_t OFF_A2  = OFF_W1F + SZ_W1F;
constexpr size_t SZ_A2   = (size_t)256 * 25600 * 2;           // 13,107,200
constexpr size_t OFF_X   = OFF_A2 + SZ_A2;
constexpr size_t SZ_X    = (size_t)32 * 90 * 120 * 256 * 2;   // 176,947,200
constexpr size_t OFF_P   = OFF_X + SZ_X;
constexpr size_t SZ_P    = (size_t)8 * 256 * 32 * 112 * 2;    // 14,680,064 (bf16, s=8)
// tail scratch aliases the X region (X dead after k2):
constexpr size_t OFF_UP  = OFF_X;                             // bf16 [32][3456][80] = 17.7 MB
constexpr size_t OFF_BB  = OFF_X + (size_t)24 * 1024 * 1024;  // fp32 [32][3456][5]  = 2.2 MB
constexpr size_t OFF_S0  = OFF_X + (size_t)28 * 1024 * 1024;  // fp32 [32][27][80]   = 276 KB
constexpr size_t OFF_S1  = OFF_X + (size_t)29 * 1024 * 1024;
constexpr size_t WS_NEED = OFF_P + SZ_P;                      // ~207 MB (unchanged)

// ---------------- K0a: conv1_w -> bf16 MFMA-fragment-major (16x16x32, v3 layout) ---------
// w1f flat index = ((kh*16 + ocb)*5 + kwc)*512 + lane*8 + j
//   element = w1[(ocb*16 + (lane&15)) * 4800 + kh*160 + kwc*32 + (lane>>4)*8 + j]
__global__ void k0_w1(const float* __restrict__ w, ushort_t* __restrict__ o) {
    int t = blockIdx.x * 256 + threadIdx.x;   // grid 600*256 == 153,600 exactly
    int l   = t & 63;
    int q   = t >> 6;                          // 0..2399
    int kwc = q % 5;
    int ocb = (q / 5) % 16;
    int kh  = q / 80;
    const float* src = w + (size_t)(ocb * 16 + (l & 15)) * 4800 + kh * 160 + kwc * 32 + (l >> 4) * 8;
    float4 f0 = *(const float4*)src;
    float4 f1 = *(const float4*)(src + 4);
    uint4 pk;
    pk.x = (uint)f2bf(f0.x) | ((uint)f2bf(f0.y) << 16);
    pk.y = (uint)f2bf(f0.z) | ((uint)f2bf(f0.w) << 16);
    pk.z = (uint)f2bf(f1.x) | ((uint)f2bf(f1.y) << 16);
    pk.w = (uint)f2bf(f1.z) | ((uint)f2bf(f1.w) << 16);
    *(uint4*)&o[(size_t)t * 8] = pk;
}

// ---------------- K0b: prim_w (oc2,ic,ph,pw) -> A2[oc2][p*256+ic] bf16 ----------------
__global__ void k0_a2(const float* __restrict__ w, ushort_t* __restrict__ o) {
    __shared__ ushort_t l[25600];
    int oc2 = blockIdx.x;                     // grid 256
    const float* src = w + (size_t)oc2 * 25600;
    for (int idx = threadIdx.x; idx < 25600; idx += 256) l[idx] = f2bf(src[idx]); // idx = ic*100+p
    __syncthreads();
    ushort_t* dst = o + (size_t)oc2 * 25600;
    for (int idx = threadIdx.x; idx < 25600; idx += 256) {    // idx = p*256+ic (coalesced write)
        int p = idx >> 8, ic = idx & 255;
        dst[idx] = l[ic * 100 + p];
    }
}

// ---------------- K1: conv1+bias+relu (v3 verbatim: the proven 648-656 us config) --------
// grid (90, 32) = (h, b); 256 threads = 4 waves, wave tile 64 oc x 128 w (120 valid).
// A fragments: coalesced dwordx4 from w1f (L2-resident), deduplicated across waves.
// B: all 30 input rows staged to LDS once (zero-padded to 704); barrier-free K-loop;
// B-frag dedup: addr = f(2*nt+kwc) -> only 19 distinct LDS frags/wave-kh (16x16 ONLY;
// 32x32x16 breaks this dedup -> 53% MfmaUtil, r8).
// REGISTER NOTE: 128 VGPR + 128 AGPR = 256 total = the exact 2-waves/SIMD budget; zero
// headroom. min-waves=3 spills acc (85 GB HBM, r5); A-prefetch dbuf (+160 regs) also cannot fit.
// LDS: brow[30][704] = 42.2 KB; epilogue aliases cs[120][264] = 63.4 KB -> 2 blocks/CU.
__global__ __launch_bounds__(256, 2) void k1_conv1(const float* __restrict__ inp,
                                                   const ushort_t* __restrict__ w1f,
                                                   const float* __restrict__ cb,
                                                   ushort_t* __restrict__ X) {
    __shared__ ushort_t smem[31680];          // 63,360 B
    ushort_t* brow = smem;                    // [30][704]
    const int tid = threadIdx.x, lane = tid & 63, wid = tid >> 6;
    const int wm = wid * 64;                  // M-group: 0/64/128/192
    const int h = blockIdx.x, b = blockIdx.y;
    const int l16 = lane & 15, g8 = (lane >> 4) * 8;
    const int bbase = 4 * l16 + g8;
    f32x4 acc[4][8] = {};

    // stage 30 input rows (h..h+29) as bf16, cols 640..703 zeroed
    for (int idx = tid; idx < 5280; idx += 256) {
        int r = idx / 176, c = idx % 176;
        uint2 pk; pk.x = 0u; pk.y = 0u;
        if (c < 160) {
            const float* irow = inp + ((size_t)b * 120 + h + r) * 640;
            float4 f = *(const float4*)&irow[c * 4];
            pk.x = (uint)f2bf(f.x) | ((uint)f2bf(f.y) << 16);
            pk.y = (uint)f2bf(f.z) | ((uint)f2bf(f.w) << 16);
        }
        *(uint2*)&brow[r * 704 + c * 4] = pk;
    }
    __syncthreads();

#pragma unroll 1
    for (int kh = 0; kh < 30; ++kh) {
        // B-fragment cache: 19 frags, t = 2*nt + kwc
        bf16x8 bc[19];
        const int rb = kh * 704 + bbase;
#pragma unroll
        for (int t = 0; t < 19; ++t) {
            union { bf16x8 v8; bf16x4 v4[2]; } fr;
            fr.v4[0] = *(const bf16x4*)&brow[rb + 32 * t];
            fr.v4[1] = *(const bf16x4*)&brow[rb + 32 * t + 4];
            bc[t] = fr.v8;
        }
#pragma unroll
        for (int kwc = 0; kwc < 5; ++kwc) {
            bf16x8 af[4];
#pragma unroll
            for (int mt = 0; mt < 4; ++mt) {
                int q = (kh * 16 + wid * 4 + mt) * 5 + kwc;
                af[mt] = *(const bf16x8*)&w1f[(size_t)q * 512 + lane * 8];
            }
#pragma unroll
            for (int nt = 0; nt < 8; ++nt)
#pragma unroll
                for (int mt = 0; mt < 4; ++mt)
                    acc[mt][nt] = __builtin_amdgcn_mfma_f32_16x16x32_bf16(af[mt], bc[2 * nt + kwc], acc[mt][nt], 0, 0, 0);
        }
    }

    // epilogue: bias+relu -> LDS transpose cs[120 w][264 (256 oc + pad)] -> coalesced store
    float cbv[4][4];
#pragma unroll
    for (int mt = 0; mt < 4; ++mt)
#pragma unroll
        for (int r = 0; r < 4; ++r)
            cbv[mt][r] = cb[wm + mt * 16 + (lane >> 4) * 4 + r];
    __syncthreads();
    ushort_t* cs = smem;                      // [120][264] (stride 528B = 132 words == 4 mod 32 -> 2-way)
#pragma unroll
    for (int nt = 0; nt < 8; ++nt) {
        int wg = nt * 16 + l16;
        if (wg < 120) {
#pragma unroll
            for (int mt = 0; mt < 4; ++mt)
#pragma unroll
                for (int r = 0; r < 4; ++r) {
                    int oc = wm + mt * 16 + (lane >> 4) * 4 + r;
                    float v = acc[mt][nt][r] + cbv[mt][r];
                    v = v > 0.f ? v : 0.f;
                    cs[wg * 264 + oc] = f2bf(v);
                }
        }
    }
    __syncthreads();
    ushort_t* Xbase = X + ((size_t)b * 90 + h) * 120 * 256;
    for (int idx = tid; idx < 3840; idx += 256) {            // 120*256/8 chunks
        int w = idx >> 5, c = (idx & 31) * 8;
        *(uint4*)&Xbase[(size_t)w * 256 + c] = *(const uint4*)&cs[w * 264 + c];
    }
}

// ---------------- K2: prim conv GEMM, split-K s=8, barrier-free (r8 config) ----------------
// grid (2, 8, 32) = (oc2 half, split, b); 256 thr = 4 waves, each owning a distinct
// 32-oc slice x 112 n x the s-range of p. Patch positions partition X exactly, so no
// cross-wave reduction is needed: no LDS, no barriers. P[s][oc2][b][n] bf16.
__global__ __launch_bounds__(256) void k2_prim(const ushort_t* __restrict__ X,
                                               const ushort_t* __restrict__ A2,
                                               ushort_t* __restrict__ P) {
    const int tid = threadIdx.x, lane = tid & 63, wid = tid >> 6;
    const int mi = blockIdx.x, s = blockIdx.y, b = blockIdx.z;
    const int msub = mi * 128 + wid * 32;
    const int l16 = lane & 15, g8 = (lane >> 4) * 8;
    f32x4 acc[2][7] = {};
    size_t aoff[2];
#pragma unroll
    for (int t = 0; t < 2; ++t) aoff[t] = (size_t)(msub + t * 16 + l16) * 25600 + g8;
    size_t noff[7];
#pragma unroll
    for (int nt = 0; nt < 7; ++nt) {
        int n = nt * 16 + l16; n = n < 108 ? n : 107;   // pad cols clamp
        int h2 = n / 12, w2 = n % 12;
        noff[nt] = (((size_t)b * 90 + 10 * h2) * 120 + 10 * w2) * 256 + g8;
    }
    const int p0 = (100 * s) / 8, p1 = (100 * (s + 1)) / 8;
#pragma unroll 1
    for (int p = p0; p < p1; ++p) {
        int ph = p / 10, pw = p % 10;
        size_t xb = (size_t)(ph * 120 + pw) * 256;
        size_t ab = (size_t)p * 256;
#pragma unroll
        for (int icc = 0; icc < 8; ++icc) {
            bf16x8 af[2], bfr[7];
#pragma unroll
            for (int t = 0; t < 2; ++t)
                af[t] = *(const bf16x8*)&A2[aoff[t] + ab + icc * 32];
#pragma unroll
            for (int nt = 0; nt < 7; ++nt)
                bfr[nt] = *(const bf16x8*)&X[noff[nt] + xb + icc * 32];
#pragma unroll
            for (int t = 0; t < 2; ++t)
#pragma unroll
                for (int nt = 0; nt < 7; ++nt)
                    acc[t][nt] = __builtin_amdgcn_mfma_f32_16x16x32_bf16(af[t], bfr[nt], acc[t][nt], 0, 0, 0);
        }
    }
#pragma unroll
    for (int t = 0; t < 2; ++t)
#pragma unroll
        for (int nt = 0; nt < 7; ++nt)
#pragma unroll
            for (int r = 0; r < 4; ++r) {
                int n   = nt * 16 + l16;
                int oc2 = msub + t * 16 + (lane >> 4) * 4 + r;
                P[(((size_t)s * 256 + oc2) * 32 + b) * 112 + n] = f2bf(acc[t][nt][r]);
            }
}

// ---------------- K3: reduce partials + prim bias + squash + caps prediction ----------------
// b-interleaved: lanes 0..31 share one caps_w row (broadcast loads). UP bf16 [b][i][80].
__global__ __launch_bounds__(256) void k3_caps(const ushort_t* __restrict__ P,
                                               const float* __restrict__ prim_b,
                                               const float* __restrict__ caps_w,
                                               ushort_t* __restrict__ UP) {
    int t = blockIdx.x * 256 + threadIdx.x;   // grid 432*256 == 110,592 exactly
    int b = t & 31, i = t >> 5;
    int cap = i / 108, hw = i % 108;
    float ud[8], l2 = 0.f;
#pragma unroll
    for (int d = 0; d < 8; ++d) {
        int oc2 = cap * 8 + d;
        float v = prim_b[oc2];
#pragma unroll
        for (int s = 0; s < 8; ++s)
            v += bf2f(P[(((size_t)s * 256 + oc2) * 32 + b) * 112 + hw]);
        ud[d] = v; l2 += v * v;
    }
    float scale = sqrtf(l2) / (1.f + l2);     // squash factor
#pragma unroll
    for (int d = 0; d < 8; ++d) ud[d] *= scale;
    const float* cw = caps_w + (size_t)i * 640;
    ushort_t* up = UP + ((size_t)b * 3456 + i) * 80;
    for (int j = 0; j < 80; j += 4) {
        f32x4 o = {0.f, 0.f, 0.f, 0.f};
#pragma unroll
        for (int d = 0; d < 8; ++d) {
            f32x4 w = *(const f32x4*)&cw[d * 80 + j];
            o += ud[d] * w;
        }
        uint2 pk;
        pk.x = (uint)f2bf(o[0]) | ((uint)f2bf(o[1]) << 16);
        pk.y = (uint)f2bf(o[2]) | ((uint)f2bf(o[3]) << 16);
        *(uint2*)&up[j] = pk;
    }
}

// ---------------- K4 iteration: (optional v from spIn) + b-update + softmax + partial s ----
// grid (27, 32) x 128 thr; thread owns i = chunk*128+tid.
// flags: 1 = reduce spIn -> v and add u.v to b; 2 = read b from BB (else b_route); 4 = write BB
__global__ __launch_bounds__(128) void k4_iter(const ushort_t* __restrict__ UP,
                                               const float* __restrict__ b_route,
                                               float* __restrict__ BB,
                                               const float* __restrict__ spIn,
                                               float* __restrict__ spOut,
                                               int flags) {
    __shared__ __attribute__((aligned(16))) float sv[80];
    __shared__ float sred[2][80];
    __shared__ float sscale[5];
    const int tid = threadIdx.x, lane = tid & 63, wv = tid >> 6;
    const int chunk = blockIdx.x, b = blockIdx.y;

    if (flags & 1) {                          // reduce previous partials -> v (redundant per block, cheap)
        if (tid < 80) {
            float s = 0.f;
            for (int c2 = 0; c2 < 27; ++c2) s += spIn[((size_t)b * 27 + c2) * 80 + tid];
            sv[tid] = s;
        }
        __syncthreads();
        if (tid < 5) {
            float l2 = 0.f;
            for (int d = 0; d < 16; ++d) { float x = sv[tid * 16 + d]; l2 += x * x; }
            sscale[tid] = sqrtf(l2) / (1.f + l2);
        }
        __syncthreads();
        if (tid < 80) sv[tid] *= sscale[tid / 16];
    }
    __syncthreads();

    const int i = chunk * 128 + tid;
    const ushort_t* up = UP + ((size_t)b * 3456 + i) * 80;
    f32x4 u4[20];
#pragma unroll
    for (int r = 0; r < 20; ++r) u4[r] = up4(*(const uint2*)&up[r * 4]);

    float bo[5];
#pragma unroll
    for (int o = 0; o < 5; ++o) {
        float bv = (flags & 2) ? BB[((size_t)b * 3456 + i) * 5 + o] : b_route[i * 5 + o];
        if (flags & 1) {
            f32x4 dv = u4[o * 4 + 0] * (*(const f32x4*)&sv[o * 16 + 0])
                     + u4[o * 4 + 1] * (*(const f32x4*)&sv[o * 16 + 4])
                     + u4[o * 4 + 2] * (*(const f32x4*)&sv[o * 16 + 8])
                     + u4[o * 4 + 3] * (*(const f32x4*)&sv[o * 16 + 12]);
            bv += dv[0] + dv[1] + dv[2] + dv[3];
        }
        if (flags & 4) BB[((size_t)b * 3456 + i) * 5 + o] = bv;
        bo[o] = bv;
    }
    float m = fmaxf(fmaxf(fmaxf(bo[0], bo[1]), fmaxf(bo[2], bo[3])), bo[4]);
    float e[5], sum = 0.f;
#pragma unroll
    for (int o = 0; o < 5; ++o) { e[o] = __expf(bo[o] - m); sum += e[o]; }
    float inv = 1.f / sum;
    f32x4 a4[20];
#pragma unroll
    for (int o = 0; o < 5; ++o) {
        float c = e[o] * inv;
#pragma unroll
        for (int q = 0; q < 4; ++q) a4[o * 4 + q] = c * u4[o * 4 + q];
    }
    // reduce across 128 threads
#pragma unroll
    for (int off = 32; off >= 1; off >>= 1)
#pragma unroll
        for (int q = 0; q < 20; ++q)
#pragma unroll
            for (int c = 0; c < 4; ++c) a4[q][c] += __shfl_xor(a4[q][c], off, 64);
    if (lane == 0)
#pragma unroll
        for (int q = 0; q < 20; ++q)
#pragma unroll
            for (int c = 0; c < 4; ++c) sred[wv][q * 4 + c] = a4[q][c];
    __syncthreads();
    if (tid < 80) spOut[((size_t)b * 27 + chunk) * 80 + tid] = sred[0][tid] + sred[1][tid];
}

// ---------------- K4 final: reduce -> v -> logits -> log_softmax ----------------
__global__ __launch_bounds__(192) void k4_fin(const float* __restrict__ spIn,
                                              const float* __restrict__ pred_w,
                                              const float* __restrict__ pred_b,
                                              const float* __restrict__ eos_w,
                                              const float* __restrict__ eos_b,
                                              float* __restrict__ out) {
    __shared__ __attribute__((aligned(16))) float sv[80];
    __shared__ float sscale[5];
    __shared__ float lg[130];
    __shared__ float lse[5];
    const int tid = threadIdx.x, b = blockIdx.x;
    if (tid < 80) {
        float s = 0.f;
        for (int c2 = 0; c2 < 27; ++c2) s += spIn[((size_t)b * 27 + c2) * 80 + tid];
        sv[tid] = s;
    }
    __syncthreads();
    if (tid < 5) {
        float l2 = 0.f;
        for (int d = 0; d < 16; ++d) { float x = sv[tid * 16 + d]; l2 += x * x; }
        sscale[tid] = sqrtf(l2) / (1.f + l2);
    }
    __syncthreads();
    if (tid < 80) sv[tid] *= sscale[tid / 16];
    __syncthreads();
    if (tid < 130) {
        int o = tid / 26, j = tid % 26;
        const float* wv = (j < 25) ? &pred_w[j * 16] : &eos_w[0];
        float dot = (j < 25) ? pred_b[j] : eos_b[0];
        for (int d = 0; d < 16; ++d) dot += sv[o * 16 + d] * wv[d];
        lg[tid] = dot;
    }
    __syncthreads();
    if (tid < 5) {
        float m = lg[tid * 26];
        for (int j = 1; j < 26; ++j) m = fmaxf(m, lg[tid * 26 + j]);
        float sum = 0.f;
        for (int j = 0; j < 26; ++j) sum += expf(lg[tid * 26 + j] - m);
        lse[tid] = m + logf(sum);
    }
    __syncthreads();
    if (tid < 130) out[b * 130 + tid] = lg[tid] - lse[tid / 26];
}

// ---------------- launch ----------------
extern "C" void kernel_launch(void* const* d_in, const int* in_sizes, int n_in,
                              void* d_out, int out_size, void* d_ws, size_t ws_size,
                              hipStream_t stream) {
    const float* inp    = (const float*)d_in[0];
    const float* w1     = (const float*)d_in[1];
    const float* cb1    = (const float*)d_in[2];
    const float* w2     = (const float*)d_in[3];
    const float* pb2    = (const float*)d_in[4];
    const float* capsw  = (const float*)d_in[5];
    const float* broute = (const float*)d_in[6];
    const float* predw  = (const float*)d_in[7];
    const float* predb  = (const float*)d_in[8];
    const float* eosw   = (const float*)d_in[9];
    const float* eosb   = (const float*)d_in[10];
    float* out = (float*)d_out;
    char* ws = (char*)d_ws;
    if (ws_size < WS_NEED) return;

    ushort_t* w1f = (ushort_t*)(ws + OFF_W1F);
    ushort_t* a2  = (ushort_t*)(ws + OFF_A2);
    ushort_t* X   = (ushort_t*)(ws + OFF_X);
    ushort_t* P   = (ushort_t*)(ws + OFF_P);
    ushort_t* UP  = (ushort_t*)(ws + OFF_UP);
    float*    BB  = (float*)(ws + OFF_BB);
    float*    S0  = (float*)(ws + OFF_S0);
    float*    S1  = (float*)(ws + OFF_S1);

    k0_w1   <<<dim3(600),      dim3(256), 0, stream>>>(w1, w1f);
    k0_a2   <<<dim3(256),      dim3(256), 0, stream>>>(w2, a2);
    k1_conv1<<<dim3(90, 32),   dim3(256), 0, stream>>>(inp, w1f, cb1, X);
    k2_prim <<<dim3(2, 8, 32), dim3(256), 0, stream>>>(X, a2, P);
    k3_caps <<<dim3(432),      dim3(256), 0, stream>>>(P, pb2, capsw, UP);
    // routing: it0 (initial c/s/v) .. it3; partials double-buffered S0/S1
    k4_iter <<<dim3(27, 32),   dim3(128), 0, stream>>>(UP, broute, BB, S1, S0, 0);         // s0
    k4_iter <<<dim3(27, 32),   dim3(128), 0, stream>>>(UP, broute, BB, S0, S1, 1 | 4);     // v0; b1; s1
    k4_iter <<<dim3(27, 32),   dim3(128), 0, stream>>>(UP, broute, BB, S1, S0, 1 | 2 | 4); // v1; b2; s2
    k4_iter <<<dim3(27, 32),   dim3(128), 0, stream>>>(UP, broute, BB, S0, S1, 1 | 2);     // v2; b3; s3
    k4_fin  <<<dim3(32),       dim3(192), 0, stream>>>(S1, predw, predb, eosw, eosb, out);
}